// Round 10
// baseline (3097.405 us; speedup 1.0000x reference)
//
#include <hip/hip_runtime.h>
#include <hip/hip_fp16.h>
#include <math.h>

typedef _Float16 half_t;
typedef __attribute__((ext_vector_type(8))) _Float16 f16x8;  // MFMA A/B frag
typedef __attribute__((ext_vector_type(4))) float   f32x4;   // MFMA C/D frag
typedef __attribute__((ext_vector_type(4))) float   float4v;

#define IN_F   1536
#define HID    640
#define OUT_F  10
#define NBATCH 65536

#define SB() __builtin_amdgcn_sched_barrier(0)

// ---------- helpers ----------

__device__ __forceinline__ void gll16(const void* g, const void* l) {
    __builtin_amdgcn_global_load_lds(
        (const __attribute__((address_space(1))) unsigned*)g,
        (__attribute__((address_space(3))) unsigned*)l, 16, 0, 0);
}

// exact-GELU via A&S 7.1.26 erf poly (|eps|<=1.5e-7, noise vs f16 rounding)
__device__ __forceinline__ float gelu_fast(float z) {
    float x  = 0.70710678118654752f * z;
    float ax = fabsf(x);
    float t  = 1.0f / (1.0f + 0.3275911f * ax);
    float p  = t * (0.254829592f +
               t * (-0.284496736f +
               t * (1.421413741f +
               t * (-1.453152027f +
               t * 1.061405429f))));
    float e  = __expf(-ax * ax);
    float er = 1.0f - p * e;
    er = (x < 0.0f) ? -er : er;
    return 0.5f * z * (1.0f + er);
}

// ---------- prep: mask dtype detection + masked weight build ----------

__global__ void k_detect(const unsigned* __restrict__ m, int nDwords, int* flags) {
    int f = 0, g = 0;
    for (int i = blockIdx.x * blockDim.x + threadIdx.x; i < nDwords;
         i += gridDim.x * blockDim.x) {
        unsigned d = m[i];
        f |= (d == 0x3F800000u);
        g |= (d != 0u) & (d != 1u) & (d != 0x3F800000u);
    }
    if (f) atomicOr(&flags[0], 1);
    if (g) atomicOr(&flags[1], 1);
}

__device__ __forceinline__ bool mask_at(const void* mask, int i, int isB, int isF) {
    if (isB) return ((const unsigned char*)mask)[i] != 0;
    if (isF) return ((const float*)mask)[i] != 0.0f;
    return ((const int*)mask)[i] != 0;
}

__global__ void k_mask_all(const float* __restrict__ W1, const float* __restrict__ W2,
                           const float* __restrict__ W3,
                           const void* __restrict__ m1, const void* __restrict__ m2,
                           const void* __restrict__ m3,
                           half_t* __restrict__ W1h, half_t* __restrict__ W2h,
                           float* __restrict__ W3m, const int* __restrict__ flags) {
    const int isB = flags[1], isF = flags[0];
    const int N1 = HID * IN_F, N2 = HID * HID, N3 = OUT_F * HID;
    const int NT = N1 + N2 + N3;
    for (int i = blockIdx.x * blockDim.x + threadIdx.x; i < NT;
         i += gridDim.x * blockDim.x) {
        if (i < N1) {
            W1h[i] = mask_at(m1, i, isB, isF) ? (half_t)W1[i] : (half_t)0.0f;
        } else if (i < N1 + N2) {
            int j = i - N1;
            W2h[j] = mask_at(m2, j, isB, isF) ? (half_t)W2[j] : (half_t)0.0f;
        } else {
            int j = i - N1 - N2;
            W3m[j] = mask_at(m3, j, isB, isF) ? W3[j] : 0.0f;
        }
    }
}

// ---------- fused GEMM (+ exact GELU): full-width tile, min staged bytes ----------
// C[m][n] = gelu( sum_k A[m][k] * W[n][k] ), C f16 [NBATCH][HID].
// BM=256, BN=640 (FULL width -> A staged exactly once), BK=32.
// 1024 thr = 16 waves (4m x 4n), per-wave C = 64x160, acc[4][10] = 160 AGPR.
// Grid = 256 blocks = 1/CU. All staging via global_load_lds, depth-2 ring,
// per-wave-class counted vmcnt (R9-proven).
// LDS slabs (x2):
//   A f32: [256 rows][128B], byte = row*128 + ((slot ^ (row&7))<<4)   (R6-clean)
//   A f16 / B: pair-packed [rows/2][128B]:
//     byte = (row>>1)*128 + (((((row&1)<<2)|kq) ^ ((row>>1)&7))<<4)   (R7-clean)
// Staged bytes: L1 = 402(A,HBM-stream) + 503(B,L2) = 906 MB; L2 = 294 MB.
template <int K, bool AF32>
__global__ __launch_bounds__(1024, 1) void gemm_gelu(
    const void* __restrict__ Ain, const half_t* __restrict__ Bw,
    half_t* __restrict__ Cout) {
    constexpr int NK     = K / 32;                   // 48 or 20
    constexpr int ABYTES = AF32 ? 32768 : 16384;
    constexpr int SLAB   = ABYTES + 40960;           // + B 640 rows x 64B
    static_assert(NK >= 4, "");
    __shared__ __align__(16) char lds[2 * SLAB];     // 144KB / 112KB

    const int t = threadIdx.x, lane = t & 63, wid = t >> 6;
    const int wr = wid >> 2, wc = wid & 3;
    const long mBase = (long)blockIdx.x * 256;

    // ---- fragment read addresses ----
    const int rr = lane & 15, k8 = lane >> 4;        // k8 in [0,4)
    int aRd0[4], aRd1[4], bRd[10];
#pragma unroll
    for (int mf = 0; mf < 4; ++mf) {
        const int row = wr * 64 + mf * 16 + rr;
        if constexpr (AF32) {
            aRd0[mf] = row * 128 + (((2 * k8)     ^ (row & 7)) << 4);
            aRd1[mf] = row * 128 + (((2 * k8 + 1) ^ (row & 7)) << 4);
        } else {
            const int ln = row >> 1;
            aRd0[mf] = ln * 128 + ((((((row & 1) << 2) | k8) ^ (ln & 7))) << 4);
        }
    }
#pragma unroll
    for (int nf = 0; nf < 10; ++nf) {
        const int nrow = wc * 160 + nf * 16 + rr;
        const int ln   = nrow >> 1;
        bRd[nf] = ABYTES + ln * 128 + ((((((nrow & 1) << 2) | k8) ^ (ln & 7))) << 4);
    }

    // ---- staging sources (inverse-swizzled), linear gll dests ----
    // A f32 (2 ops): o=(t+j*1024)*16 -> row=(t>>3)+j*128, slot=t&7, kq=slot^(row&7)
    //   ((row+128)&7 == row&7 -> same kq for both ops)
    // A f16 (1 op): o=t*16 -> line=t>>3, slot=t&7, orig=slot^(line&7),
    //   row=2*line+(orig>>2), kq=orig&3
    // B (4 ops, t<640): o=(t+r*640)*16 -> line=(t>>3)+r*80, slot=t&7 (640%8==0),
    //   (line&7) invariant in r (80%8==0) -> nrow = base + r*160, kq fixed
    const float*  srcAf0 = nullptr; const float* srcAf1 = nullptr;
    const half_t* srcAh  = nullptr;
    if constexpr (AF32) {
        const int row = t >> 3, kq = (t & 7) ^ ((t >> 3) & 7);
        srcAf0 = (const float*)Ain + (mBase + row) * (long)K + kq * 4;
        srcAf1 = srcAf0 + (size_t)128 * K;
    } else {
        const int ln = t >> 3, orig = (t & 7) ^ (ln & 7);
        const int row = 2 * ln + (orig >> 2), kq = orig & 3;
        srcAh = (const half_t*)Ain + (mBase + row) * (long)K + kq * 8;
    }
    const half_t* srcB0 = nullptr;
    {
        const int ln = t >> 3, orig = (t & 7) ^ (ln & 7);
        const int nrow = 2 * ln + (orig >> 2), kq = orig & 3;
        srcB0 = Bw + (size_t)nrow * K + kq * 8;
    }

    auto STAGE = [&](int k, int sb) {
        const size_t koff = (size_t)k * 32;
        if constexpr (AF32) {
            gll16(srcAf0 + koff, &lds[sb + t * 16]);
            gll16(srcAf1 + koff, &lds[sb + t * 16 + 16384]);
        } else {
            gll16(srcAh + koff, &lds[sb + t * 16]);
        }
        if (t < 640) {
#pragma unroll
            for (int r = 0; r < 4; ++r)
                gll16(srcB0 + (size_t)r * 160 * K + koff,
                      &lds[sb + ABYTES + (t + r * 640) * 16]);
        }
    };

    f32x4 acc[4][10];
#pragma unroll
    for (int mf = 0; mf < 4; ++mf)
#pragma unroll
        for (int nf = 0; nf < 10; ++nf) {
            f32x4 z = {0.f, 0.f, 0.f, 0.f};
            acc[mf][nf] = z;
        }

    STAGE(0, 0); SB();
    STAGE(1, SLAB); SB();

    for (int ks = 0; ks < NK; ++ks) {
        const int cb = (ks & 1) * SLAB;
        // entry: retire L(ks), keep L(ks+1) (per-wave-class outstanding counts)
        if (ks + 1 < NK) {
            if constexpr (AF32) {
                if (wid < 10) asm volatile("s_waitcnt vmcnt(6)" ::: "memory");
                else          asm volatile("s_waitcnt vmcnt(2)" ::: "memory");
            } else {
                if (wid < 10) asm volatile("s_waitcnt vmcnt(5)" ::: "memory");
                else          asm volatile("s_waitcnt vmcnt(1)" ::: "memory");
            }
        } else {
            asm volatile("s_waitcnt vmcnt(0)" ::: "memory");
        }
        __builtin_amdgcn_s_barrier();                    // READY: slab ks complete
        float4v alo[4], ahi[4];
        f16x8 av[4], bv[10];
        if constexpr (AF32) {
#pragma unroll
            for (int mf = 0; mf < 4; ++mf) {
                alo[mf] = *(const float4v*)(&lds[cb + aRd0[mf]]);
                ahi[mf] = *(const float4v*)(&lds[cb + aRd1[mf]]);
            }
        } else {
#pragma unroll
            for (int mf = 0; mf < 4; ++mf)
                av[mf] = *(const f16x8*)(&lds[cb + aRd0[mf]]);
        }
#pragma unroll
        for (int nf = 0; nf < 10; ++nf)
            bv[nf] = *(const f16x8*)(&lds[cb + bRd[nf]]);
        asm volatile("s_waitcnt lgkmcnt(0)" ::: "memory");
        SB();                                             // rule 18
        if (ks + 2 < NK) {
            __builtin_amdgcn_s_barrier();                 // CONSUMED: safe overwrite
            STAGE(ks + 2, cb);
            SB();
        }
        if constexpr (AF32) {
#pragma unroll
            for (int mf = 0; mf < 4; ++mf) {
                f16x8 h;
#pragma unroll
                for (int i = 0; i < 4; ++i) {
                    h[i]     = (half_t)alo[mf][i];
                    h[i + 4] = (half_t)ahi[mf][i];
                }
                av[mf] = h;
            }
        }
#pragma unroll
        for (int mf = 0; mf < 4; ++mf)
#pragma unroll
            for (int nf = 0; nf < 10; ++nf)
                acc[mf][nf] = __builtin_amdgcn_mfma_f32_16x16x32_f16(
                    av[mf], bv[nf], acc[mf][nf], 0, 0, 0);
    }

    // epilogue: C/D frag col=lane&15, row=(lane>>4)*4+j (verified mapping)
    const int crow0 = (lane >> 4) * 4;
    const int ccol  = lane & 15;
#pragma unroll
    for (int mf = 0; mf < 4; ++mf)
#pragma unroll
        for (int nf = 0; nf < 10; ++nf)
#pragma unroll
            for (int j = 0; j < 4; ++j) {
                const long row = mBase + wr * 64 + mf * 16 + crow0 + j;
                const int  col = wc * 160 + nf * 16 + ccol;
                Cout[row * HID + col] = (half_t)gelu_fast(acc[mf][nf][j]);
            }
}

// ---------- layer 3: out[b][o] = sum_k h2[b][k] * W3m[o][k], K=640, O=10 ----------
__global__ __launch_bounds__(256) void layer3_kernel(
    const half_t* __restrict__ h2, const float* __restrict__ W3m,
    float* __restrict__ out) {
    const int t = threadIdx.x, lane = t & 63, w = t >> 6;
    float w3r[OUT_F][10];
#pragma unroll
    for (int o = 0; o < OUT_F; ++o)
#pragma unroll
        for (int j = 0; j < 10; ++j)
            w3r[o][j] = W3m[o * HID + j * 64 + lane];

    for (long row = (long)blockIdx.x * 4 + w; row < NBATCH; row += (long)gridDim.x * 4) {
        float acc[OUT_F];
#pragma unroll
        for (int o = 0; o < OUT_F; ++o) acc[o] = 0.f;
        const half_t* hr = h2 + row * HID;
#pragma unroll
        for (int j = 0; j < 10; ++j) {
            const float h = (float)hr[j * 64 + lane];
#pragma unroll
            for (int o = 0; o < OUT_F; ++o) acc[o] += h * w3r[o][j];
        }
#pragma unroll
        for (int o = 0; o < OUT_F; ++o) {
            float v = acc[o];
#pragma unroll
            for (int off = 32; off >= 1; off >>= 1) v += __shfl_xor(v, off);
            if (lane == o) out[row * OUT_F + o] = v;
        }
    }
}

// ---------- launch ----------

extern "C" void kernel_launch(void* const* d_in, const int* in_sizes, int n_in,
                              void* d_out, int out_size, void* d_ws, size_t ws_size,
                              hipStream_t stream) {
    const float* x  = (const float*)d_in[0];
    const float* W1 = (const float*)d_in[1];
    const float* W2 = (const float*)d_in[2];
    const float* W3 = (const float*)d_in[3];
    const void*  m1 = d_in[4];
    const void*  m2 = d_in[5];
    const void*  m3 = d_in[6];
    float* out = (float*)d_out;

    char* ws = (char*)d_ws;
    int*    flags = (int*)ws;
    half_t* W1h = (half_t*)(ws + 256);                      // 640*1536*2
    half_t* W2h = (half_t*)(ws + 256 + 1966080);            // 640*640*2
    float*  W3m = (float*)(ws + 256 + 1966080 + 819200);    // 25600
    half_t* h1  = (half_t*)(ws + 256 + 1966080 + 819200 + 25600);
    half_t* h2  = (half_t*)((char*)h1 + (size_t)NBATCH * HID * 2);

    hipMemsetAsync(flags, 0, 8, stream);
    k_detect<<<64, 256, 0, stream>>>((const unsigned*)m1, 65536, flags);
    k_mask_all<<<1024, 256, 0, stream>>>(W1, W2, W3, m1, m2, m3, W1h, W2h, W3m, flags);

    gemm_gelu<IN_F, true><<<256, 1024, 0, stream>>>((const void*)x, W1h, h1);
    gemm_gelu<HID, false><<<256, 1024, 0, stream>>>((const void*)h1, W2h, h2);
    layer3_kernel<<<2048, 256, 0, stream>>>(h2, W3m, out);
}

// Round 11
// 327.739 us; speedup vs baseline: 9.4508x; 9.4508x over previous
//
#include <hip/hip_runtime.h>
#include <hip/hip_fp16.h>
#include <math.h>

typedef _Float16 half_t;
typedef __attribute__((ext_vector_type(8))) _Float16 f16x8;  // MFMA A/B frag
typedef __attribute__((ext_vector_type(4))) float   f32x4;   // MFMA C/D frag
typedef __attribute__((ext_vector_type(4))) float   float4v;

#define IN_F   1536
#define HID    640
#define OUT_F  10
#define NBATCH 65536

#define SB() __builtin_amdgcn_sched_barrier(0)

// ---------- helpers ----------

__device__ __forceinline__ void gll16(const void* g, const void* l) {
    __builtin_amdgcn_global_load_lds(
        (const __attribute__((address_space(1))) unsigned*)g,
        (__attribute__((address_space(3))) unsigned*)l, 16, 0, 0);
}

// exact-GELU via A&S 7.1.26 erf poly (|eps|<=1.5e-7, noise vs f16 rounding)
__device__ __forceinline__ float gelu_fast(float z) {
    float x  = 0.70710678118654752f * z;
    float ax = fabsf(x);
    float t  = 1.0f / (1.0f + 0.3275911f * ax);
    float p  = t * (0.254829592f +
               t * (-0.284496736f +
               t * (1.421413741f +
               t * (-1.453152027f +
               t * 1.061405429f))));
    float e  = __expf(-ax * ax);
    float er = 1.0f - p * e;
    er = (x < 0.0f) ? -er : er;
    return 0.5f * z * (1.0f + er);
}

// ---------- prep: mask dtype detection + masked weight build ----------

__global__ void k_detect(const unsigned* __restrict__ m, int nDwords, int* flags) {
    int f = 0, g = 0;
    for (int i = blockIdx.x * blockDim.x + threadIdx.x; i < nDwords;
         i += gridDim.x * blockDim.x) {
        unsigned d = m[i];
        f |= (d == 0x3F800000u);
        g |= (d != 0u) & (d != 1u) & (d != 0x3F800000u);
    }
    if (f) atomicOr(&flags[0], 1);
    if (g) atomicOr(&flags[1], 1);
}

__device__ __forceinline__ bool mask_at(const void* mask, int i, int isB, int isF) {
    if (isB) return ((const unsigned char*)mask)[i] != 0;
    if (isF) return ((const float*)mask)[i] != 0.0f;
    return ((const int*)mask)[i] != 0;
}

__global__ void k_mask_all(const float* __restrict__ W1, const float* __restrict__ W2,
                           const float* __restrict__ W3,
                           const void* __restrict__ m1, const void* __restrict__ m2,
                           const void* __restrict__ m3,
                           half_t* __restrict__ W1h, half_t* __restrict__ W2h,
                           float* __restrict__ W3m, const int* __restrict__ flags) {
    const int isB = flags[1], isF = flags[0];
    const int N1 = HID * IN_F, N2 = HID * HID, N3 = OUT_F * HID;
    const int NT = N1 + N2 + N3;
    for (int i = blockIdx.x * blockDim.x + threadIdx.x; i < NT;
         i += gridDim.x * blockDim.x) {
        if (i < N1) {
            W1h[i] = mask_at(m1, i, isB, isF) ? (half_t)W1[i] : (half_t)0.0f;
        } else if (i < N1 + N2) {
            int j = i - N1;
            W2h[j] = mask_at(m2, j, isB, isF) ? (half_t)W2[j] : (half_t)0.0f;
        } else {
            int j = i - N1 - N2;
            W3m[j] = mask_at(m3, j, isB, isF) ? W3[j] : 0.0f;
        }
    }
}

// ---------- fused GEMM (+ exact GELU): 3-slab single-barrier ring ----------
// C[m][n] = gelu( sum_k A[m][k] * W[n][k] ), C f16 [NBATCH][HID].
// BM=256, BN=320, BK=32. 512 thr = 8 waves (2m x 4n), per-wave C = 128x80,
// acc[8][5] = 160 VGPR (cap 256 at 2 waves/SIMD -> no spill).
// LDS: 3 slabs (ring) x (A + B), ONE s_barrier per K-step:
//   iter ks: vmcnt(class) retire L(ks); barrier READY(ks); STAGE(ks+2) into
//   slab (ks+2)%3  [= (ks-1)%3, whose reads completed before this barrier via
//   each wave's lgkm-before-MFMA dependency -> race-free]; read frags from
//   slab ks%3; MFMA. Loads run ~2 K-steps ahead, never drained mid-loop.
// Layouts (measured conflict-free):
//   A f32 (AF32): [256 rows][128B], byte = row*128 + ((slot^(row&7))<<4)
//   A f16 / B: pair-packed [rows/2][128B]:
//     byte = ln*128 + (((((row&1)<<2)|kq) ^ (ln&7))<<4), ln = row>>1
// gll16 dests linear; sources inverse-swizzled.
// Staged bytes: G1 = 804(A f32) + 503(B) = 1307 MB; G2 = 164 + 210 = 374 MB.
template <int K, bool AF32>
__global__ __launch_bounds__(512, 2) void gemm_gelu(
    const void* __restrict__ Ain, const half_t* __restrict__ Bw,
    half_t* __restrict__ Cout) {
    constexpr int NK     = K / 32;                    // 48 or 20
    constexpr int ABYTES = AF32 ? 32768 : 16384;      // 256 x 32 x (4|2)B
    constexpr int SLAB   = ABYTES + 20480;            // + B 320 x 32 x 2B
    constexpr int CL0    = AF32 ? 7 : 5;              // waves 0-3 ops/tile
    constexpr int CL1    = AF32 ? 6 : 4;              // waves 4-7 ops/tile
    static_assert(NK >= 4, "");
    __shared__ __align__(16) char lds[3 * SLAB];      // 156KB / 108KB

    const int t = threadIdx.x, lane = t & 63, wid = t >> 6;
    const int wr = wid >> 2, wc = wid & 3;

    // XCD-bijective swizzle; nwg = 512 = 8*64, n-fastest (2 n-blocks/panel).
    const int q       = (int)gridDim.x >> 3;
    const int logical = ((int)blockIdx.x & 7) * q + ((int)blockIdx.x >> 3);
    const int mb = logical >> 1, nbk = logical & 1;
    const long mBase = (long)mb * 256;
    const int  n0    = nbk * 320;

    // ---- fragment read address bases (mf offset: +2048 f32 / +1024 f16) ----
    const int rr = lane & 15, k8 = lane >> 4;
    int aBase0 = 0, aBase1 = 0, bBase = 0;
    {
        const int row = wr * 128 + rr;
        if constexpr (AF32) {
            aBase0 = row * 128 + (((2 * k8) ^ (row & 7)) << 4);
            aBase1 = aBase0 ^ 16;
        } else {
            const int ln = row >> 1;
            aBase0 = ln * 128 + ((((((row & 1) << 2) | k8)) ^ (ln & 7)) << 4);
        }
        const int nrow = wc * 80 + rr, lnb = nrow >> 1;
        bBase = ABYTES + lnb * 128 +
                ((((((nrow & 1) << 2) | k8)) ^ (lnb & 7)) << 4);
    }

    // ---- staging sources (inverse-swizzled), linear gll dests ----
    const float*  srcAf = nullptr;
    const half_t* srcAh = nullptr;
    if constexpr (AF32) {
        // 4 ops/thr: o=(t+r*512)*16 -> row=(t>>3)+64r, slot=t&7, kq=slot^(row&7)
        const int row = t >> 3, kq = (t & 7) ^ ((t >> 3) & 7);
        srcAf = (const float*)Ain + (mBase + row) * (long)K + kq * 4;
    } else {
        // 2 ops/thr: o=(t+r*512)*16 -> line=(t>>3)+64r, slot=t&7,
        // orig=slot^(line&7), row=2*line+(orig>>2), kq=orig&3
        const int line = t >> 3, orig = (t & 7) ^ (line & 7);
        const int row = 2 * line + (orig >> 2), kq = orig & 3;
        srcAh = (const half_t*)Ain + (mBase + row) * (long)K + kq * 8;
    }
    const half_t* srcB;
    {
        const int line = t >> 3, orig = (t & 7) ^ (line & 7);
        const int nrow = 2 * line + (orig >> 2), kq = orig & 3;
        srcB = Bw + (size_t)(n0 + nrow) * K + kq * 8;
    }

    auto STAGE = [&](int k, int sb) {
        const size_t ko = (size_t)k * 32;
        if constexpr (AF32) {
#pragma unroll
            for (int r = 0; r < 4; ++r)
                gll16(srcAf + ko + (size_t)r * 64 * K,
                      &lds[sb + (t + r * 512) * 16]);
        } else {
#pragma unroll
            for (int r = 0; r < 2; ++r)
                gll16(srcAh + ko + (size_t)r * 128 * K,
                      &lds[sb + (t + r * 512) * 16]);
        }
#pragma unroll
        for (int r = 0; r < 2; ++r)
            gll16(srcB + ko + (size_t)r * 128 * K,
                  &lds[sb + ABYTES + (t + r * 512) * 16]);
        if (t < 256)
            gll16(srcB + ko + (size_t)2 * 128 * K,
                  &lds[sb + ABYTES + (t + 1024) * 16]);
    };

    f32x4 acc[8][5];
#pragma unroll
    for (int mf = 0; mf < 8; ++mf)
#pragma unroll
        for (int nf = 0; nf < 5; ++nf) {
            f32x4 z = {0.f, 0.f, 0.f, 0.f};
            acc[mf][nf] = z;
        }

    // prologue: L(0) -> slab0, L(1) -> slab1
    STAGE(0, 0); SB();
    STAGE(1, SLAB); SB();

    for (int ks = 0; ks < NK; ++ks) {
        // entry: retire own L(ks) ops, keep L(ks+1) in flight
        if (ks + 1 < NK) {
            if (wid < 4) asm volatile("s_waitcnt vmcnt(%0)" :: "i"(CL0) : "memory");
            else         asm volatile("s_waitcnt vmcnt(%0)" :: "i"(CL1) : "memory");
        } else {
            asm volatile("s_waitcnt vmcnt(0)" ::: "memory");
        }
        __builtin_amdgcn_s_barrier();                 // READY(ks): slab ks%3 full,
                                                      // all reads of ks-1 done
        const int cb = (ks % 3) * SLAB;
        if (ks + 2 < NK) { STAGE(ks + 2, ((ks + 2) % 3) * SLAB); SB(); }

        f16x8 bv[5];
#pragma unroll
        for (int nf = 0; nf < 5; ++nf)
            bv[nf] = *(const f16x8*)(&lds[cb + bBase + nf * 1024]);
        f16x8 av[8];
        if constexpr (AF32) {
#pragma unroll
            for (int mf = 0; mf < 8; ++mf) {
                float4v alo = *(const float4v*)(&lds[cb + aBase0 + mf * 2048]);
                float4v ahi = *(const float4v*)(&lds[cb + aBase1 + mf * 2048]);
                f16x8 h;
#pragma unroll
                for (int i = 0; i < 4; ++i) {
                    h[i]     = (half_t)alo[i];
                    h[i + 4] = (half_t)ahi[i];
                }
                av[mf] = h;
            }
        } else {
#pragma unroll
            for (int mf = 0; mf < 8; ++mf)
                av[mf] = *(const f16x8*)(&lds[cb + aBase0 + mf * 1024]);
        }
#pragma unroll
        for (int mf = 0; mf < 8; ++mf)
#pragma unroll
            for (int nf = 0; nf < 5; ++nf)
                acc[mf][nf] = __builtin_amdgcn_mfma_f32_16x16x32_f16(
                    av[mf], bv[nf], acc[mf][nf], 0, 0, 0);
    }

    // epilogue: C/D frag col=lane&15, row=(lane>>4)*4+j (verified mapping)
    const int crow0 = (lane >> 4) * 4;
    const int ccol  = lane & 15;
#pragma unroll
    for (int mf = 0; mf < 8; ++mf)
#pragma unroll
        for (int nf = 0; nf < 5; ++nf)
#pragma unroll
            for (int j = 0; j < 4; ++j) {
                const long row = mBase + wr * 128 + mf * 16 + crow0 + j;
                const int  col = n0 + wc * 80 + nf * 16 + ccol;
                Cout[row * HID + col] = (half_t)gelu_fast(acc[mf][nf][j]);
            }
}

// ---------- layer 3: out[b][o] = sum_k h2[b][k] * W3m[o][k], K=640, O=10 ----------
__global__ __launch_bounds__(256) void layer3_kernel(
    const half_t* __restrict__ h2, const float* __restrict__ W3m,
    float* __restrict__ out) {
    const int t = threadIdx.x, lane = t & 63, w = t >> 6;
    float w3r[OUT_F][10];
#pragma unroll
    for (int o = 0; o < OUT_F; ++o)
#pragma unroll
        for (int j = 0; j < 10; ++j)
            w3r[o][j] = W3m[o * HID + j * 64 + lane];

    for (long row = (long)blockIdx.x * 4 + w; row < NBATCH; row += (long)gridDim.x * 4) {
        float acc[OUT_F];
#pragma unroll
        for (int o = 0; o < OUT_F; ++o) acc[o] = 0.f;
        const half_t* hr = h2 + row * HID;
#pragma unroll
        for (int j = 0; j < 10; ++j) {
            const float h = (float)hr[j * 64 + lane];
#pragma unroll
            for (int o = 0; o < OUT_F; ++o) acc[o] += h * w3r[o][j];
        }
#pragma unroll
        for (int o = 0; o < OUT_F; ++o) {
            float v = acc[o];
#pragma unroll
            for (int off = 32; off >= 1; off >>= 1) v += __shfl_xor(v, off);
            if (lane == o) out[row * OUT_F + o] = v;
        }
    }
}

// ---------- launch ----------

extern "C" void kernel_launch(void* const* d_in, const int* in_sizes, int n_in,
                              void* d_out, int out_size, void* d_ws, size_t ws_size,
                              hipStream_t stream) {
    const float* x  = (const float*)d_in[0];
    const float* W1 = (const float*)d_in[1];
    const float* W2 = (const float*)d_in[2];
    const float* W3 = (const float*)d_in[3];
    const void*  m1 = d_in[4];
    const void*  m2 = d_in[5];
    const void*  m3 = d_in[6];
    float* out = (float*)d_out;

    char* ws = (char*)d_ws;
    int*    flags = (int*)ws;
    half_t* W1h = (half_t*)(ws + 256);                      // 640*1536*2
    half_t* W2h = (half_t*)(ws + 256 + 1966080);            // 640*640*2
    float*  W3m = (float*)(ws + 256 + 1966080 + 819200);    // 25600
    half_t* h1  = (half_t*)(ws + 256 + 1966080 + 819200 + 25600);
    half_t* h2  = (half_t*)((char*)h1 + (size_t)NBATCH * HID * 2);

    hipMemsetAsync(flags, 0, 8, stream);
    k_detect<<<64, 256, 0, stream>>>((const unsigned*)m1, 65536, flags);
    k_mask_all<<<1024, 256, 0, stream>>>(W1, W2, W3, m1, m2, m3, W1h, W2h, W3m, flags);

    gemm_gelu<IN_F, true><<<512, 512, 0, stream>>>((const void*)x, W1h, h1);
    gemm_gelu<HID, false><<<512, 512, 0, stream>>>((const void*)h1, W2h, h2);
    layer3_kernel<<<2048, 256, 0, stream>>>(h2, W3m, out);
}